// Round 13
// baseline (3251.939 us; speedup 1.0000x reference)
//
#include <hip/hip_runtime.h>
#include <hip/hip_bf16.h>
#include <math.h>

#define NBANDS 400
#define NPIX   65536
#define FFW    128
#define KSEL   10
#define TOK    16
#define HS     403    // repair h stride (f64)
#define FS     131    // repair f stride (f64)
#define HSF    404    // main h stride (f32), %4==0 for b128
#define FSF    132    // main f stride (f32)
#define TAU    1e-3f
#define LISTCAP 16384

typedef double f64x4 __attribute__((ext_vector_type(4)));
typedef float  f32x4 __attribute__((ext_vector_type(4)));
#define MFMA64(a,b,c) __builtin_amdgcn_mfma_f64_16x16x4f64((a),(b),(c),0,0,0)

// ---- ws byte offsets ----
static constexpr size_t WSB_WVOT  = 0;          // f64 [2][400][400] WvoT[l][k][j]=(Wo@Wv)[j][k]
static constexpr size_t WSB_BVO   = 2560000;    // f64 [2][400]
static constexpr size_t WSB_SIG   = 2566400;    // f64 [400]
static constexpr size_t WSB_W1T   = 2569600;    // f32 [2][400][128]
static constexpr size_t WSB_W2T   = 2979200;    // f32 [2][128][400]
static constexpr size_t WSB_WVOTF = 3388800;    // f32 [2][400][400]
static constexpr size_t WSB_CNT   = 4668800;    // int counter
static constexpr size_t WSB_LIST  = 4668864;    // int [16384]
static constexpr size_t WS_NEED   = 4734400;

// ---- out offsets (fp32 elements) ----
static constexpr size_t REC_OFF = 0;
static constexpr size_t IDX_OFF = 26214400;
static constexpr size_t SCO_OFF = IDX_OFF + 655360;
static constexpr size_t SEL_OFF = SCO_OFF + 26214400;
static constexpr int    OUT_EXPECT = 53739520;

// ---------------- prep kernels ----------------

__global__ void prep_wvot(const float* __restrict__ Wv, const float* __restrict__ Wo,
                          double* __restrict__ WvoT) {
    int b = blockIdx.x;
    int l = b / 400, j = b - l * 400;
    int k = threadIdx.x;
    if (k >= 400) return;
    const float* wo = Wo + l * 160000 + j * 400;
    const float* wv = Wv + l * 160000;
    double acc = 0.0;
    #pragma unroll 4
    for (int m = 0; m < 400; ++m)
        acc += (double)wo[m] * (double)wv[m * 400 + k];
    WvoT[l * 160000 + k * 400 + j] = acc;
}

__global__ void prep_wvotf(const double* __restrict__ WvoT, float* __restrict__ WvoTf) {
    int i = blockIdx.x * blockDim.x + threadIdx.x;
    if (i < 320000) WvoTf[i] = (float)WvoT[i];
}

__global__ void prep_transpose(const float* __restrict__ W1, const float* __restrict__ W2,
                               float* __restrict__ W1T, float* __restrict__ W2T) {
    int idx = blockIdx.x * blockDim.x + threadIdx.x;
    if (idx < 2 * FFW * NBANDS) {
        int l = idx / (FFW * NBANDS); int r = idx - l * (FFW * NBANDS);
        int jf = r / NBANDS; int k = r - jf * NBANDS;
        W1T[l * FFW * NBANDS + k * FFW + jf] = W1[idx];
        int j = r / FFW; int kf = r - j * FFW;
        W2T[l * FFW * NBANDS + kf * NBANDS + j] = W2[idx];
    }
}

__global__ void prep_small(const float* __restrict__ Wo, const float* __restrict__ bv,
                           const float* __restrict__ bo, const float* __restrict__ bi,
                           double* __restrict__ bvo, double* __restrict__ sigd) {
    int g = blockIdx.x * blockDim.x + threadIdx.x;
    if (g < 800) {
        int l = g / 400;
        const float* wo = Wo + l * 160000 + (g - l * 400) * 400;
        const float* bb = bv + l * 400;
        double acc = (double)bo[g];
        for (int m = 0; m < 400; ++m) acc += (double)wo[m] * (double)bb[m];
        bvo[g] = acc;
    } else if (g < 1200) {
        int c = g - 800;
        sigd[c] = 1.0 / (1.0 + exp(-(double)bi[c]));
    }
}

__global__ void zero_cnt(int* cnt) { if (threadIdx.x == 0) *cnt = 0; }

__global__ void sentinel_kernel(float* out, float v) {
    out[blockIdx.x * 256 + threadIdx.x] = v;
}

// ---------------- main (fast, fp32 VALU) kernel ----------------
// 16 tokens/WG, 512 threads = 8 waves; LDS 38016 B -> up to 4 WGs/CU.
// GEMM map (attn/FF2): tg=tid>>7 -> TM=4 tokens; cx=tid&127 -> TN=3 cols
// (0..383); tail cols 384..399 on tid<256 (tt=tid>>4, jt=384+(tid&15)).
// A-operands: wave-broadcast ds_read_b128 (4 consecutive k). Weights k-major,
// wave-contiguous scalar loads (768B/wave/k). Tokens with top-10 margin < TAU
// flagged for exact fp64-MFMA repair (mechanism proven in r12).

__device__ inline void ln_f32(float* __restrict__ hf, float* __restrict__ redf,
                              const float* __restrict__ w, const float* __restrict__ b, int tid) {
    {
        int t = tid >> 5, q = tid & 31;
        float s = 0.f, ss = 0.f;
        for (int j = q; j < NBANDS; j += 32) {
            float v = hf[t * HSF + j]; s += v; ss += v * v;
        }
        #pragma unroll
        for (int m = 1; m < 32; m <<= 1) {
            s  += __shfl_xor(s, m, 64);
            ss += __shfl_xor(ss, m, 64);
        }
        if (q == 0) { redf[t * 2] = s; redf[t * 2 + 1] = ss; }
    }
    __syncthreads();
    for (int idx = tid; idx < TOK * NBANDS; idx += 512) {
        int t = idx / NBANDS, j = idx - t * NBANDS;
        float mu  = redf[t * 2] * (1.0f / 400.0f);
        float var = redf[t * 2 + 1] * (1.0f / 400.0f) - mu * mu;
        float rs  = 1.0f / sqrtf(var + 1e-5f);
        hf[t * HSF + j] = (hf[t * HSF + j] - mu) * rs * w[j] + b[j];
    }
    __syncthreads();
}

__global__ __launch_bounds__(512) void hbsm_fast(
    const float* __restrict__ x, const float* __restrict__ xo,
    const float* __restrict__ pos,
    const float* __restrict__ ln1w, const float* __restrict__ ln1b,
    const float* __restrict__ b1,   const float* __restrict__ b2,
    const float* __restrict__ ln2w, const float* __restrict__ ln2b,
    const float* __restrict__ We1,  const float* __restrict__ be1,
    const float* __restrict__ We2,  const float* __restrict__ be2,
    const float* __restrict__ Wd1,  const float* __restrict__ bd1,
    const float* __restrict__ Wd2,  const float* __restrict__ bd2,
    const double* __restrict__ bvo, const double* __restrict__ sigd,
    const float* __restrict__ WvoTf, const float* __restrict__ W1Tf,
    const float* __restrict__ W2Tf,
    int* __restrict__ cnt, int* __restrict__ list,
    float* __restrict__ out)
{
    extern __shared__ char smemc[];
    float* hf    = (float*)smemc;                 // 16*404
    float* ff    = (float*)(smemc + 25856);       // 16*132
    float* sigsf = (float*)(smemc + 34304);       // 400
    float* redf  = (float*)(smemc + 35904);       // 32
    float* lvalf = (float*)(smemc + 36032);       // 16*11
    int*   lidx  = (int*)(smemc + 36736);         // 16*11
    float* d1sf  = (float*)(smemc + 37440);       // 16*9

    const int tid = threadIdx.x;
    const int p0  = blockIdx.x * TOK;

    for (int i = tid; i < NBANDS; i += 512) sigsf[i] = (float)sigd[i];
    for (int i = tid; i < TOK * NBANDS; i += 512) {
        int t = i & 15, c = i >> 4;
        float xv = __builtin_nontemporal_load(&x[(size_t)c * NPIX + p0 + t]);
        hf[t * HSF + c] = xv + pos[c];
    }
    __syncthreads();

    const int tg = tid >> 7;              // 0..3, wave-uniform
    const int cx = tid & 127;
    const int t0 = tg * 4;
    const int jb = cx * 3;
    const bool tailw = (tid < 256);       // waves 0..3
    const int tt = tid >> 4, jt = 384 + (tid & 15);

    for (int l = 0; l < 2; ++l) {
        // ---- attention: hf += h @ Wvo^T + bvo ; LN1 ----
        {
            const float* WT = WvoTf + l * 160000;
            float acc[4][3];
            #pragma unroll
            for (int i = 0; i < 4; ++i)
                #pragma unroll
                for (int n = 0; n < 3; ++n) acc[i][n] = 0.f;
            float acct = 0.f;
            #pragma unroll 2
            for (int k4 = 0; k4 < NBANDS; k4 += 4) {
                f32x4 av0 = *(const f32x4*)&hf[(t0 + 0) * HSF + k4];
                f32x4 av1 = *(const f32x4*)&hf[(t0 + 1) * HSF + k4];
                f32x4 av2 = *(const f32x4*)&hf[(t0 + 2) * HSF + k4];
                f32x4 av3 = *(const f32x4*)&hf[(t0 + 3) * HSF + k4];
                f32x4 tav = tailw ? *(const f32x4*)&hf[tt * HSF + k4] : (f32x4){0,0,0,0};
                #pragma unroll
                for (int kk = 0; kk < 4; ++kk) {
                    const float* wr = WT + (size_t)(k4 + kk) * 400;
                    float w0 = wr[jb], w1 = wr[jb + 1], w2 = wr[jb + 2];
                    acc[0][0] += av0[kk] * w0; acc[0][1] += av0[kk] * w1; acc[0][2] += av0[kk] * w2;
                    acc[1][0] += av1[kk] * w0; acc[1][1] += av1[kk] * w1; acc[1][2] += av1[kk] * w2;
                    acc[2][0] += av2[kk] * w0; acc[2][1] += av2[kk] * w1; acc[2][2] += av2[kk] * w2;
                    acc[3][0] += av3[kk] * w0; acc[3][1] += av3[kk] * w1; acc[3][2] += av3[kk] * w2;
                    if (tailw) acct += tav[kk] * wr[jt];
                }
            }
            __syncthreads();   // all reads of hf done before in-place update
            #pragma unroll
            for (int i = 0; i < 4; ++i) {
                hf[(t0 + i) * HSF + jb]     += acc[i][0] + (float)bvo[l * 400 + jb];
                hf[(t0 + i) * HSF + jb + 1] += acc[i][1] + (float)bvo[l * 400 + jb + 1];
                hf[(t0 + i) * HSF + jb + 2] += acc[i][2] + (float)bvo[l * 400 + jb + 2];
            }
            if (tailw) hf[tt * HSF + jt] += acct + (float)bvo[l * 400 + jt];
            __syncthreads();
        }
        ln_f32(hf, redf, ln1w + l * 400, ln1b + l * 400, tid);

        // ---- FF1: ff = relu(h @ W1^T + b1) ; col jf = cx ----
        {
            const float* WT = W1Tf + (size_t)l * 51200;
            const int jf = cx;
            float acc[4] = {0.f, 0.f, 0.f, 0.f};
            #pragma unroll 2
            for (int k4 = 0; k4 < NBANDS; k4 += 4) {
                f32x4 av0 = *(const f32x4*)&hf[(t0 + 0) * HSF + k4];
                f32x4 av1 = *(const f32x4*)&hf[(t0 + 1) * HSF + k4];
                f32x4 av2 = *(const f32x4*)&hf[(t0 + 2) * HSF + k4];
                f32x4 av3 = *(const f32x4*)&hf[(t0 + 3) * HSF + k4];
                #pragma unroll
                for (int kk = 0; kk < 4; ++kk) {
                    float w = WT[(size_t)(k4 + kk) * FFW + jf];
                    acc[0] += av0[kk] * w; acc[1] += av1[kk] * w;
                    acc[2] += av2[kk] * w; acc[3] += av3[kk] * w;
                }
            }
            float bias = b1[l * FFW + jf];
            #pragma unroll
            for (int i = 0; i < 4; ++i) {
                float v = acc[i] + bias;
                ff[(t0 + i) * FSF + jf] = v > 0.f ? v : 0.f;
            }
            __syncthreads();   // ff visible (also fences FF1's hf reads)
        }

        // ---- FF2: hf += f @ W2^T + b2 ; LN2 ----
        {
            const float* WT = W2Tf + (size_t)l * 51200;
            float acc[4][3];
            #pragma unroll
            for (int i = 0; i < 4; ++i)
                #pragma unroll
                for (int n = 0; n < 3; ++n) acc[i][n] = 0.f;
            float acct = 0.f;
            #pragma unroll 2
            for (int k4 = 0; k4 < FFW; k4 += 4) {
                f32x4 av0 = *(const f32x4*)&ff[(t0 + 0) * FSF + k4];
                f32x4 av1 = *(const f32x4*)&ff[(t0 + 1) * FSF + k4];
                f32x4 av2 = *(const f32x4*)&ff[(t0 + 2) * FSF + k4];
                f32x4 av3 = *(const f32x4*)&ff[(t0 + 3) * FSF + k4];
                f32x4 tav = tailw ? *(const f32x4*)&ff[tt * FSF + k4] : (f32x4){0,0,0,0};
                #pragma unroll
                for (int kk = 0; kk < 4; ++kk) {
                    const float* wr = WT + (size_t)(k4 + kk) * 400;
                    float w0 = wr[jb], w1 = wr[jb + 1], w2 = wr[jb + 2];
                    acc[0][0] += av0[kk] * w0; acc[0][1] += av0[kk] * w1; acc[0][2] += av0[kk] * w2;
                    acc[1][0] += av1[kk] * w0; acc[1][1] += av1[kk] * w1; acc[1][2] += av1[kk] * w2;
                    acc[2][0] += av2[kk] * w0; acc[2][1] += av2[kk] * w1; acc[2][2] += av2[kk] * w2;
                    acc[3][0] += av3[kk] * w0; acc[3][1] += av3[kk] * w1; acc[3][2] += av3[kk] * w2;
                    if (tailw) acct += tav[kk] * wr[jt];
                }
            }
            // only ff is read; hf writes owner-disjoint
            #pragma unroll
            for (int i = 0; i < 4; ++i) {
                hf[(t0 + i) * HSF + jb]     += acc[i][0] + b2[l * 400 + jb];
                hf[(t0 + i) * HSF + jb + 1] += acc[i][1] + b2[l * 400 + jb + 1];
                hf[(t0 + i) * HSF + jb + 2] += acc[i][2] + b2[l * 400 + jb + 2];
            }
            if (tailw) hf[tt * HSF + jt] += acct + b2[l * 400 + jt];
            __syncthreads();
        }
        ln_f32(hf, redf, ln2w + l * 400, ln2b + l * 400, tid);
    }

    // ---- scores output ----
    for (int idx = tid; idx < TOK * NBANDS; idx += 512) {
        int t = idx / NBANDS, c = idx - t * NBANDS;
        __builtin_nontemporal_store(hf[t * HSF + c] * sigsf[c],
                                    &out[SCO_OFF + (size_t)(p0 + t) * NBANDS + c]);
    }

    // ---- top-11 + margin flag + approx outputs ----
    if (tid < TOK) {
        int t = tid;
        float* lv = lvalf + t * 11;
        int*   li = lidx + t * 11;
        #pragma unroll
        for (int k = 0; k < 11; ++k) { lv[k] = -3.0e38f; li[k] = 0; }
        for (int c = 0; c < NBANDS; ++c) {
            float v = hf[t * HSF + c] * sigsf[c];
            if (v > lv[10]) {
                int j = 10;
                while (j > 0 && lv[j - 1] < v) {
                    lv[j] = lv[j - 1]; li[j] = li[j - 1]; --j;
                }
                lv[j] = v; li[j] = c;
            }
        }
        float margin = lv[9] - lv[10];
        if (margin < TAU) {
            int slot = atomicAdd(cnt, 1);
            if (slot < LISTCAP) list[slot] = p0 + t;
        }
        for (int a = 1; a < KSEL; ++a) {      // sort top-10 by band index
            float v = lv[a]; int ci = li[a];
            int bq = a - 1;
            while (bq >= 0 && li[bq] > ci) {
                lv[bq + 1] = lv[bq]; li[bq + 1] = li[bq]; --bq;
            }
            lv[bq + 1] = v; li[bq + 1] = ci;
        }
        float sel[KSEL];
        #pragma unroll
        for (int k = 0; k < KSEL; ++k) {
            int ci = li[k];
            float band = __builtin_nontemporal_load(&xo[(size_t)ci * NPIX + p0 + t]);
            __builtin_nontemporal_store((float)ci, &out[IDX_OFF + (size_t)(p0 + t) * KSEL + k]);
            __builtin_nontemporal_store(band, &out[SEL_OFF + (size_t)(p0 + t) * KSEL + k]);
            sel[k] = band * lv[k];
        }
        float e1[8], e2[8];
        #pragma unroll
        for (int e = 0; e < 8; ++e) {
            float acc = be1[e];
            #pragma unroll
            for (int k = 0; k < KSEL; ++k) acc += sel[k] * We1[e * KSEL + k];
            e1[e] = acc > 0.f ? acc : 0.f;
        }
        #pragma unroll
        for (int e = 0; e < 8; ++e) {
            float acc = be2[e];
            #pragma unroll
            for (int j = 0; j < 8; ++j) acc += e1[j] * We2[e * 8 + j];
            e2[e] = acc;
        }
        #pragma unroll
        for (int e = 0; e < 8; ++e) {
            float acc = bd1[e];
            #pragma unroll
            for (int j = 0; j < 8; ++j) acc += e2[j] * Wd1[e * 8 + j];
            d1sf[t * 9 + e] = acc > 0.f ? acc : 0.f;
        }
    }
    __syncthreads();

    for (int idx = tid; idx < TOK * NBANDS; idx += 512) {
        int t = idx & 15, c = idx >> 4;
        float acc = bd2[c];
        const float* w = Wd2 + c * 8;
        #pragma unroll
        for (int e = 0; e < 8; ++e) acc += d1sf[t * 9 + e] * w[e];
        __builtin_nontemporal_store(acc, &out[REC_OFF + (size_t)c * NPIX + p0 + t]);
    }
}

// ---------------- repair kernel (exact fp64 MFMA, token-list; r12-proven) ----------------

__device__ inline void layer_norm_inplace(double* __restrict__ h, double* __restrict__ red,
                                          const float* __restrict__ w, const float* __restrict__ b,
                                          int tid) {
    {
        int t = tid >> 5, q = tid & 31;
        double s = 0.0, ss = 0.0;
        for (int j = q; j < NBANDS; j += 32) {
            double v = h[t * HS + j]; s += v; ss += v * v;
        }
        #pragma unroll
        for (int m = 1; m < 32; m <<= 1) {
            s  += __shfl_xor(s, m, 64);
            ss += __shfl_xor(ss, m, 64);
        }
        if (q == 0) { red[t * 2] = s; red[t * 2 + 1] = ss; }
    }
    __syncthreads();
    for (int idx = tid; idx < TOK * NBANDS; idx += 512) {
        int t = idx / NBANDS, j = idx - t * NBANDS;
        double mu  = red[t * 2] / 400.0;
        double var = red[t * 2 + 1] / 400.0 - mu * mu;
        double rs  = 1.0 / sqrt(var + 1e-5);
        h[t * HS + j] = (h[t * HS + j] - mu) * rs * (double)w[j] + (double)b[j];
    }
    __syncthreads();
}

__global__ __launch_bounds__(512) void hbsm_repair(
    const float* __restrict__ x, const float* __restrict__ xo,
    const float* __restrict__ pos,
    const float* __restrict__ ln1w, const float* __restrict__ ln1b,
    const float* __restrict__ b1,   const float* __restrict__ b2,
    const float* __restrict__ ln2w, const float* __restrict__ ln2b,
    const float* __restrict__ We1,  const float* __restrict__ be1,
    const float* __restrict__ We2,  const float* __restrict__ be2,
    const float* __restrict__ Wd1,  const float* __restrict__ bd1,
    const float* __restrict__ Wd2,  const float* __restrict__ bd2,
    const double* __restrict__ WvoT, const double* __restrict__ bvo,
    const double* __restrict__ sigd,
    const float* __restrict__ W1Tf,  const float* __restrict__ W2Tf,
    const int* __restrict__ cnt, const int* __restrict__ list,
    float* __restrict__ out)
{
    const int n = *cnt;
    if ((int)blockIdx.x * TOK >= n) return;

    extern __shared__ double smem[];
    double* h    = smem;
    double* f    = h + TOK * HS;
    double* red  = f + TOK * FS;
    double* lval = red + 64;
    double* sigs = lval + 160;
    float*  d1s  = (float*)(sigs + 400);
    int*    lidx = (int*)(d1s + 144);
    int*    ptok = (int*)(lidx + 160);

    const int tid  = threadIdx.x;
    const int lane = tid & 63;
    const int wv   = tid >> 6;
    const int rA   = lane & 15;
    const int kq   = lane >> 4;

    if (tid < TOK) {
        int slot = blockIdx.x * TOK + tid;
        ptok[tid] = (slot < n && slot < LISTCAP) ? list[slot] : -1;
    }

    int rowm[4], colm[4];
    {
        f64x4 z = {0.0, 0.0, 0.0, 0.0};
        f64x4 pr = MFMA64(0.25 * (double)rA, 1.0, z);
        f64x4 pc = MFMA64(0.25, (double)rA, z);
        #pragma unroll
        for (int i = 0; i < 4; ++i) {
            rowm[i] = ((int)(pr[i] + 0.5)) & 15;
            colm[i] = ((int)(pc[i] + 0.5)) & 15;
        }
    }

    for (int i = tid; i < NBANDS; i += 512) sigs[i] = sigd[i];
    __syncthreads();
    for (int i = tid; i < TOK * NBANDS; i += 512) {
        int t = i & 15, c = i >> 4;
        int pt = ptok[t];
        h[t * HS + c] = (pt >= 0) ? ((double)x[(size_t)c * NPIX + pt] + (double)pos[c]) : 0.0;
    }
    __syncthreads();

    const double* hA = h + rA * HS;
    const int c0 = wv * 16 + rA, c1 = c0 + 128, c2 = c0 + 256;
    const int ct = 384 + rA;
    const bool xtraA = (wv == 0);
    const bool xtraF = (wv == 4);

    for (int l = 0; l < 2; ++l) {
        {
            const double* WT  = WvoT + l * 160000;
            const double* bb0 = bvo + l * 400;
            f64x4 a0={0,0,0,0}, a1={0,0,0,0}, a2={0,0,0,0}, a3={0,0,0,0};
            #pragma unroll 2
            for (int k0 = 0; k0 < NBANDS; k0 += 4) {
                double av = hA[k0 + kq];
                const double* wrow = WT + (size_t)(k0 + kq) * 400;
                a0 = MFMA64(av, wrow[c0], a0);
                a1 = MFMA64(av, wrow[c1], a1);
                a2 = MFMA64(av, wrow[c2], a2);
                if (xtraA) a3 = MFMA64(av, wrow[ct], a3);
            }
            __syncthreads();
            #pragma unroll
            for (int i = 0; i < 4; ++i) {
                int r  = rowm[i];
                int j0 = wv * 16 + colm[i], j1 = j0 + 128, j2 = j0 + 256;
                h[r * HS + j0] += a0[i] + bb0[j0];
                h[r * HS + j1] += a1[i] + bb0[j1];
                h[r * HS + j2] += a2[i] + bb0[j2];
                if (xtraA) {
                    int jtl = 384 + colm[i];
                    h[r * HS + jtl] += a3[i] + bb0[jtl];
                }
            }
            __syncthreads();
        }
        layer_norm_inplace(h, red, ln1w + l * 400, ln1b + l * 400, tid);

        {
            const float* WT  = W1Tf + (size_t)l * 51200;
            const float* bb1 = b1 + l * FFW;
            const int cf = wv * 16 + rA;
            f64x4 e0 = {0,0,0,0};
            #pragma unroll 2
            for (int k0 = 0; k0 < NBANDS; k0 += 4) {
                double av = hA[k0 + kq];
                double b = (double)WT[(size_t)(k0 + kq) * FFW + cf];
                e0 = MFMA64(av, b, e0);
            }
            #pragma unroll
            for (int i = 0; i < 4; ++i) {
                int r  = rowm[i];
                int jf = wv * 16 + colm[i];
                double v0 = e0[i] + (double)bb1[jf];
                f[r * FS + jf] = v0 > 0.0 ? v0 : 0.0;
            }
            __syncthreads();
        }

        {
            const float* WT  = W2Tf + (size_t)l * 51200;
            const float* bb2 = b2 + l * 400;
            const double* fA = f + rA * FS;
            f64x4 a0={0,0,0,0}, a1={0,0,0,0}, a2={0,0,0,0}, a3={0,0,0,0};
            #pragma unroll 2
            for (int k0 = 0; k0 < FFW; k0 += 4) {
                double av = fA[k0 + kq];
                const float* wrow = WT + (size_t)(k0 + kq) * 400;
                a0 = MFMA64(av, (double)wrow[c0], a0);
                a1 = MFMA64(av, (double)wrow[c1], a1);
                a2 = MFMA64(av, (double)wrow[c2], a2);
                if (xtraF) a3 = MFMA64(av, (double)wrow[ct], a3);
            }
            #pragma unroll
            for (int i = 0; i < 4; ++i) {
                int r  = rowm[i];
                int j0 = wv * 16 + colm[i], j1 = j0 + 128, j2 = j0 + 256;
                h[r * HS + j0] += a0[i] + (double)bb2[j0];
                h[r * HS + j1] += a1[i] + (double)bb2[j1];
                h[r * HS + j2] += a2[i] + (double)bb2[j2];
                if (xtraF) {
                    int jtl = 384 + colm[i];
                    h[r * HS + jtl] += a3[i] + (double)bb2[jtl];
                }
            }
            __syncthreads();
        }
        layer_norm_inplace(h, red, ln2w + l * 400, ln2b + l * 400, tid);
    }

    for (int idx = tid; idx < TOK * NBANDS; idx += 512) {
        int t = idx / NBANDS, c = idx - t * NBANDS;
        if (ptok[t] >= 0)
            out[SCO_OFF + (size_t)ptok[t] * NBANDS + c] = (float)(h[t * HS + c] * sigs[c]);
    }

    if (tid < TOK && ptok[tid] >= 0) {
        int t = tid, pt = ptok[t];
        double* lv = lval + t * KSEL;
        int*    li = lidx + t * KSEL;
        #pragma unroll
        for (int k = 0; k < KSEL; ++k) { lv[k] = -1.0e300; li[k] = 0; }
        for (int c = 0; c < NBANDS; ++c) {
            double v = h[t * HS + c] * sigs[c];
            if (v > lv[KSEL - 1]) {
                int j = KSEL - 1;
                while (j > 0 && lv[j - 1] < v) {
                    lv[j] = lv[j - 1]; li[j] = li[j - 1]; --j;
                }
                lv[j] = v; li[j] = c;
            }
        }
        for (int a = 1; a < KSEL; ++a) {
            double v = lv[a]; int ci = li[a];
            int bq = a - 1;
            while (bq >= 0 && li[bq] > ci) {
                lv[bq + 1] = lv[bq]; li[bq + 1] = li[bq]; --bq;
            }
            lv[bq + 1] = v; li[bq + 1] = ci;
        }
        double sel[KSEL];
        #pragma unroll
        for (int k = 0; k < KSEL; ++k) {
            int ci = li[k];
            float band = xo[(size_t)ci * NPIX + pt];
            out[IDX_OFF + (size_t)pt * KSEL + k] = (float)ci;
            out[SEL_OFF + (size_t)pt * KSEL + k] = band;
            sel[k] = (double)band * lv[k];
        }
        double e1[8], e2[8];
        #pragma unroll
        for (int e = 0; e < 8; ++e) {
            double acc = (double)be1[e];
            #pragma unroll
            for (int k = 0; k < KSEL; ++k) acc += sel[k] * (double)We1[e * KSEL + k];
            e1[e] = acc > 0.0 ? acc : 0.0;
        }
        #pragma unroll
        for (int e = 0; e < 8; ++e) {
            double acc = (double)be2[e];
            #pragma unroll
            for (int j = 0; j < 8; ++j) acc += e1[j] * (double)We2[e * 8 + j];
            e2[e] = acc;
        }
        #pragma unroll
        for (int e = 0; e < 8; ++e) {
            double acc = (double)bd1[e];
            #pragma unroll
            for (int j = 0; j < 8; ++j) acc += e2[j] * (double)Wd1[e * 8 + j];
            d1s[t * 9 + e] = (float)(acc > 0.0 ? acc : 0.0);
        }
    }
    __syncthreads();

    for (int idx = tid; idx < TOK * NBANDS; idx += 512) {
        int t = idx & 15, c = idx >> 4;
        if (ptok[t] < 0) continue;
        double acc = (double)bd2[c];
        const float* w = Wd2 + c * 8;
        #pragma unroll
        for (int e = 0; e < 8; ++e) acc += (double)d1s[t * 9 + e] * (double)w[e];
        out[REC_OFF + (size_t)c * NPIX + ptok[t]] = (float)acc;
    }
}

// ---------------- launch ----------------
extern "C" void kernel_launch(void* const* d_in, const int* in_sizes, int n_in,
                              void* d_out, int out_size, void* d_ws, size_t ws_size,
                              hipStream_t stream) {
    if (ws_size < WS_NEED) {
        sentinel_kernel<<<dim3(256), dim3(256), 0, stream>>>((float*)d_out, -777.0f);
        return;
    }
    if (out_size != OUT_EXPECT) {
        sentinel_kernel<<<dim3(1), dim3(1), 0, stream>>>((float*)d_out, 1.0e6f);
        return;
    }
    const float* x    = (const float*)d_in[0];
    const float* xo   = (const float*)d_in[1];
    const float* pos  = (const float*)d_in[2];
    const float* bi   = (const float*)d_in[3];
    const float* Wv   = (const float*)d_in[4];
    const float* bv   = (const float*)d_in[5];
    const float* Wo   = (const float*)d_in[6];
    const float* bo   = (const float*)d_in[7];
    const float* ln1w = (const float*)d_in[8];
    const float* ln1b = (const float*)d_in[9];
    const float* W1   = (const float*)d_in[10];
    const float* b1   = (const float*)d_in[11];
    const float* W2   = (const float*)d_in[12];
    const float* b2   = (const float*)d_in[13];
    const float* ln2w = (const float*)d_in[14];
    const float* ln2b = (const float*)d_in[15];
    const float* We1  = (const float*)d_in[16];
    const float* be1  = (const float*)d_in[17];
    const float* We2  = (const float*)d_in[18];
    const float* be2  = (const float*)d_in[19];
    const float* Wd1  = (const float*)d_in[20];
    const float* bd1  = (const float*)d_in[21];
    const float* Wd2  = (const float*)d_in[22];
    const float* bd2  = (const float*)d_in[23];

    char* wsb = (char*)d_ws;
    double* WvoT  = (double*)(wsb + WSB_WVOT);
    double* bvo   = (double*)(wsb + WSB_BVO);
    double* sigd  = (double*)(wsb + WSB_SIG);
    float*  W1Tf  = (float*)(wsb + WSB_W1T);
    float*  W2Tf  = (float*)(wsb + WSB_W2T);
    float*  WvoTf = (float*)(wsb + WSB_WVOTF);
    int*    cnt   = (int*)(wsb + WSB_CNT);
    int*    list  = (int*)(wsb + WSB_LIST);

    zero_cnt<<<dim3(1), dim3(64), 0, stream>>>(cnt);
    prep_wvot<<<dim3(800), dim3(512), 0, stream>>>(Wv, Wo, WvoT);
    prep_wvotf<<<dim3(625), dim3(512), 0, stream>>>(WvoT, WvoTf);
    prep_transpose<<<dim3(400), dim3(256), 0, stream>>>(W1, W2, W1Tf, W2Tf);
    prep_small<<<dim3(5), dim3(256), 0, stream>>>(Wo, bv, bo, bi, bvo, sigd);

    const int smem_fast = 38016;
    hipFuncSetAttribute((const void*)hbsm_fast,
                        hipFuncAttributeMaxDynamicSharedMemorySize, smem_fast);
    hipLaunchKernelGGL(hbsm_fast, dim3(4096), dim3(512), smem_fast, stream,
                       x, xo, pos, ln1w, ln1b, b1, b2, ln2w, ln2b,
                       We1, be1, We2, be2, Wd1, bd1, Wd2, bd2,
                       bvo, sigd, WvoTf, W1Tf, W2Tf, cnt, list, (float*)d_out);

    const int smem_rep = 74624;
    hipFuncSetAttribute((const void*)hbsm_repair,
                        hipFuncAttributeMaxDynamicSharedMemorySize, smem_rep);
    hipLaunchKernelGGL(hbsm_repair, dim3(1024), dim3(512), smem_rep, stream,
                       x, xo, pos, ln1w, ln1b, b1, b2, ln2w, ln2b,
                       We1, be1, We2, be2, Wd1, bd1, Wd2, bd2,
                       WvoT, bvo, sigd, W1Tf, W2Tf, cnt, list, (float*)d_out);
    (void)in_sizes; (void)n_in;
}

// Round 14
// 2665.894 us; speedup vs baseline: 1.2198x; 1.2198x over previous
//
#include <hip/hip_runtime.h>
#include <hip/hip_bf16.h>
#include <math.h>

#define NBANDS 400
#define NPIX   65536
#define FFW    128
#define KSEL   10
#define TOK    16
#define HS     403    // repair h stride (f64)
#define FS     131    // repair f stride (f64)
#define HSF    404    // main h stride (f32)
#define FSF    132    // main f stride (f32)
#define WPAD   512    // padded weight row (f32)
#define TAU    1e-3f
#define LISTCAP 16384

typedef double f64x4 __attribute__((ext_vector_type(4)));
typedef float  f32x4 __attribute__((ext_vector_type(4)));
#define MFMA64(a,b,c) __builtin_amdgcn_mfma_f64_16x16x4f64((a),(b),(c),0,0,0)

// ---- ws byte offsets ----
static constexpr size_t WSB_WVOT = 0;          // f64 [2][400][400] WvoT[l][k][j]=(Wo@Wv)[j][k]
static constexpr size_t WSB_BVO  = 2560000;    // f64 [2][400]
static constexpr size_t WSB_SIG  = 2566400;    // f64 [400]
static constexpr size_t WSB_W1T  = 2569600;    // f32 [2][400][128]
static constexpr size_t WSB_W2T  = 2979200;    // f32 [2][128][400]
static constexpr size_t WSB_WVP  = 3388800;    // f32 [2][400][512] zero-padded
static constexpr size_t WSB_W2P  = 5027200;    // f32 [2][128][512] zero-padded
static constexpr size_t WSB_CNT  = 5551488;    // int counter
static constexpr size_t WSB_LIST = 5551552;    // int [16384]
static constexpr size_t WS_NEED  = 5617088;

// ---- out offsets (fp32 elements) ----
static constexpr size_t REC_OFF = 0;
static constexpr size_t IDX_OFF = 26214400;
static constexpr size_t SCO_OFF = IDX_OFF + 655360;
static constexpr size_t SEL_OFF = SCO_OFF + 26214400;
static constexpr int    OUT_EXPECT = 53739520;

// ---------------- prep kernels ----------------

__global__ void prep_wvot(const float* __restrict__ Wv, const float* __restrict__ Wo,
                          double* __restrict__ WvoT) {
    int b = blockIdx.x;
    int l = b / 400, j = b - l * 400;
    int k = threadIdx.x;
    if (k >= 400) return;
    const float* wo = Wo + l * 160000 + j * 400;
    const float* wv = Wv + l * 160000;
    double acc = 0.0;
    #pragma unroll 4
    for (int m = 0; m < 400; ++m)
        acc += (double)wo[m] * (double)wv[m * 400 + k];
    WvoT[l * 160000 + k * 400 + j] = acc;
}

__global__ void prep_transpose(const float* __restrict__ W1, const float* __restrict__ W2,
                               float* __restrict__ W1T, float* __restrict__ W2T) {
    int idx = blockIdx.x * blockDim.x + threadIdx.x;
    if (idx < 2 * FFW * NBANDS) {
        int l = idx / (FFW * NBANDS); int r = idx - l * (FFW * NBANDS);
        int jf = r / NBANDS; int k = r - jf * NBANDS;
        W1T[l * FFW * NBANDS + k * FFW + jf] = W1[idx];
        int j = r / FFW; int kf = r - j * FFW;
        W2T[l * FFW * NBANDS + kf * NBANDS + j] = W2[idx];
    }
}

// zero-padded fp32 copies: WvoP [2][400][512], W2P [2][128][512]
__global__ void prep_padf(const double* __restrict__ WvoT, const float* __restrict__ W2T,
                          float* __restrict__ WvoP, float* __restrict__ W2P) {
    int i = blockIdx.x * blockDim.x + threadIdx.x;
    if (i < 2 * 400 * WPAD) {
        int l = i / (400 * WPAD), r = i % (400 * WPAD), k = r / WPAD, c = r % WPAD;
        WvoP[i] = (c < 400) ? (float)WvoT[(size_t)l * 160000 + (size_t)k * 400 + c] : 0.f;
    }
    if (i < 2 * FFW * WPAD) {
        int l = i / (FFW * WPAD), r = i % (FFW * WPAD), k = r / WPAD, c = r % WPAD;
        W2P[i] = (c < 400) ? W2T[(size_t)l * 51200 + (size_t)k * 400 + c] : 0.f;
    }
}

__global__ void prep_small(const float* __restrict__ Wo, const float* __restrict__ bv,
                           const float* __restrict__ bo, const float* __restrict__ bi,
                           double* __restrict__ bvo, double* __restrict__ sigd) {
    int g = blockIdx.x * blockDim.x + threadIdx.x;
    if (g < 800) {
        int l = g / 400;
        const float* wo = Wo + l * 160000 + (g - l * 400) * 400;
        const float* bb = bv + l * 400;
        double acc = (double)bo[g];
        for (int m = 0; m < 400; ++m) acc += (double)wo[m] * (double)bb[m];
        bvo[g] = acc;
    } else if (g < 1200) {
        int c = g - 800;
        sigd[c] = 1.0 / (1.0 + exp(-(double)bi[c]));
    }
}

__global__ void zero_cnt(int* cnt) { if (threadIdx.x == 0) *cnt = 0; }

__global__ void sentinel_kernel(float* out, float v) {
    out[blockIdx.x * 256 + threadIdx.x] = v;
}

// ---------------- main (fast, fp32 VALU) kernel ----------------
// 16 tokens/WG, 512 threads = 8 waves; LDS 38016 B.
// GEMM map (attn/FF2): tg=tid>>7 -> TM=4 tokens; cx=tid&127, jb=cx*4 -> TN=4
// float4 cols from 512-padded weights (cx<100 active; no tail path).
// A-operands: wave-broadcast ds_read_b128. One coalesced float4 VMEM per k.
// Tokens with top-10 margin < TAU flagged for exact fp64-MFMA repair (r12-proven).

__device__ inline void ln_f32(float* __restrict__ hf, float* __restrict__ redf,
                              const float* __restrict__ w, const float* __restrict__ b, int tid) {
    {
        int t = tid >> 5, q = tid & 31;
        float s = 0.f, ss = 0.f;
        for (int j = q; j < NBANDS; j += 32) {
            float v = hf[t * HSF + j]; s += v; ss += v * v;
        }
        #pragma unroll
        for (int m = 1; m < 32; m <<= 1) {
            s  += __shfl_xor(s, m, 64);
            ss += __shfl_xor(ss, m, 64);
        }
        if (q == 0) { redf[t * 2] = s; redf[t * 2 + 1] = ss; }
    }
    __syncthreads();
    for (int idx = tid; idx < TOK * NBANDS; idx += 512) {
        int t = idx / NBANDS, j = idx - t * NBANDS;
        float mu  = redf[t * 2] * (1.0f / 400.0f);
        float var = redf[t * 2 + 1] * (1.0f / 400.0f) - mu * mu;
        float rs  = 1.0f / sqrtf(var + 1e-5f);
        hf[t * HSF + j] = (hf[t * HSF + j] - mu) * rs * w[j] + b[j];
    }
    __syncthreads();
}

__global__ __launch_bounds__(512) void hbsm_fast(
    const float* __restrict__ x, const float* __restrict__ xo,
    const float* __restrict__ pos,
    const float* __restrict__ ln1w, const float* __restrict__ ln1b,
    const float* __restrict__ b1,   const float* __restrict__ b2,
    const float* __restrict__ ln2w, const float* __restrict__ ln2b,
    const float* __restrict__ We1,  const float* __restrict__ be1,
    const float* __restrict__ We2,  const float* __restrict__ be2,
    const float* __restrict__ Wd1,  const float* __restrict__ bd1,
    const float* __restrict__ Wd2,  const float* __restrict__ bd2,
    const double* __restrict__ bvo, const double* __restrict__ sigd,
    const float* __restrict__ WvoP, const float* __restrict__ W1Tf,
    const float* __restrict__ W2P,
    int* __restrict__ cnt, int* __restrict__ list,
    float* __restrict__ out)
{
    extern __shared__ char smemc[];
    float* hf    = (float*)smemc;                 // 16*404
    float* ff    = (float*)(smemc + 25856);       // 16*132
    float* sigsf = (float*)(smemc + 34304);       // 400
    float* redf  = (float*)(smemc + 35904);       // 32
    float* lvalf = (float*)(smemc + 36032);       // 16*11
    int*   lidx  = (int*)(smemc + 36736);         // 16*11
    float* d1sf  = (float*)(smemc + 37440);       // 16*9

    const int tid = threadIdx.x;
    const int p0  = blockIdx.x * TOK;

    for (int i = tid; i < NBANDS; i += 512) sigsf[i] = (float)sigd[i];
    for (int i = tid; i < TOK * NBANDS; i += 512) {
        int t = i & 15, c = i >> 4;
        float xv = __builtin_nontemporal_load(&x[(size_t)c * NPIX + p0 + t]);
        hf[t * HSF + c] = xv + pos[c];
    }
    __syncthreads();

    const int tg = tid >> 7;              // 0..3, wave-uniform
    const int cx = tid & 127;
    const int t0 = tg * 4;
    const int jb = cx * 4;                // 0..508
    const bool cw = (jb < NBANDS);        // cx < 100

    for (int l = 0; l < 2; ++l) {
        // ---- attention: hf += h @ Wvo^T + bvo ; LN1 ----
        {
            const float* WT = WvoP + (size_t)l * 400 * WPAD;
            f32x4 a0 = {0,0,0,0}, a1 = {0,0,0,0}, a2 = {0,0,0,0}, a3 = {0,0,0,0};
            #pragma unroll 2
            for (int k4 = 0; k4 < NBANDS; k4 += 4) {
                f32x4 av0 = *(const f32x4*)&hf[(t0 + 0) * HSF + k4];
                f32x4 av1 = *(const f32x4*)&hf[(t0 + 1) * HSF + k4];
                f32x4 av2 = *(const f32x4*)&hf[(t0 + 2) * HSF + k4];
                f32x4 av3 = *(const f32x4*)&hf[(t0 + 3) * HSF + k4];
                #pragma unroll
                for (int kk = 0; kk < 4; ++kk) {
                    f32x4 w = *(const f32x4*)&WT[(size_t)(k4 + kk) * WPAD + jb];
                    a0 += av0[kk] * w;
                    a1 += av1[kk] * w;
                    a2 += av2[kk] * w;
                    a3 += av3[kk] * w;
                }
            }
            __syncthreads();   // all reads of hf done before in-place update
            if (cw) {
                #pragma unroll
                for (int n = 0; n < 4; ++n) {
                    float bvn = (float)bvo[l * 400 + jb + n];
                    hf[(t0 + 0) * HSF + jb + n] += a0[n] + bvn;
                    hf[(t0 + 1) * HSF + jb + n] += a1[n] + bvn;
                    hf[(t0 + 2) * HSF + jb + n] += a2[n] + bvn;
                    hf[(t0 + 3) * HSF + jb + n] += a3[n] + bvn;
                }
            }
            __syncthreads();
        }
        ln_f32(hf, redf, ln1w + l * 400, ln1b + l * 400, tid);

        // ---- FF1: ff = relu(h @ W1^T + b1) ; col jf = cx (all active) ----
        {
            const float* WT = W1Tf + (size_t)l * 51200;
            const int jf = cx;
            float acc[4] = {0.f, 0.f, 0.f, 0.f};
            #pragma unroll 2
            for (int k4 = 0; k4 < NBANDS; k4 += 4) {
                f32x4 av0 = *(const f32x4*)&hf[(t0 + 0) * HSF + k4];
                f32x4 av1 = *(const f32x4*)&hf[(t0 + 1) * HSF + k4];
                f32x4 av2 = *(const f32x4*)&hf[(t0 + 2) * HSF + k4];
                f32x4 av3 = *(const f32x4*)&hf[(t0 + 3) * HSF + k4];
                #pragma unroll
                for (int kk = 0; kk < 4; ++kk) {
                    float w = WT[(size_t)(k4 + kk) * FFW + jf];
                    acc[0] += av0[kk] * w; acc[1] += av1[kk] * w;
                    acc[2] += av2[kk] * w; acc[3] += av3[kk] * w;
                }
            }
            float bias = b1[l * FFW + jf];
            #pragma unroll
            for (int i = 0; i < 4; ++i) {
                float v = acc[i] + bias;
                ff[(t0 + i) * FSF + jf] = v > 0.f ? v : 0.f;
            }
            __syncthreads();   // ff visible (also fences FF1's hf reads)
        }

        // ---- FF2: hf += f @ W2^T + b2 ; LN2 ----
        {
            const float* WT = W2P + (size_t)l * FFW * WPAD;
            f32x4 a0 = {0,0,0,0}, a1 = {0,0,0,0}, a2 = {0,0,0,0}, a3 = {0,0,0,0};
            #pragma unroll 2
            for (int k4 = 0; k4 < FFW; k4 += 4) {
                f32x4 av0 = *(const f32x4*)&ff[(t0 + 0) * FSF + k4];
                f32x4 av1 = *(const f32x4*)&ff[(t0 + 1) * FSF + k4];
                f32x4 av2 = *(const f32x4*)&ff[(t0 + 2) * FSF + k4];
                f32x4 av3 = *(const f32x4*)&ff[(t0 + 3) * FSF + k4];
                #pragma unroll
                for (int kk = 0; kk < 4; ++kk) {
                    f32x4 w = *(const f32x4*)&WT[(size_t)(k4 + kk) * WPAD + jb];
                    a0 += av0[kk] * w;
                    a1 += av1[kk] * w;
                    a2 += av2[kk] * w;
                    a3 += av3[kk] * w;
                }
            }
            // only ff is read; hf writes owner-disjoint
            if (cw) {
                #pragma unroll
                for (int n = 0; n < 4; ++n) {
                    float bvn = b2[l * 400 + jb + n];
                    hf[(t0 + 0) * HSF + jb + n] += a0[n] + bvn;
                    hf[(t0 + 1) * HSF + jb + n] += a1[n] + bvn;
                    hf[(t0 + 2) * HSF + jb + n] += a2[n] + bvn;
                    hf[(t0 + 3) * HSF + jb + n] += a3[n] + bvn;
                }
            }
            __syncthreads();
        }
        ln_f32(hf, redf, ln2w + l * 400, ln2b + l * 400, tid);
    }

    // ---- scores output ----
    for (int idx = tid; idx < TOK * NBANDS; idx += 512) {
        int t = idx / NBANDS, c = idx - t * NBANDS;
        __builtin_nontemporal_store(hf[t * HSF + c] * sigsf[c],
                                    &out[SCO_OFF + (size_t)(p0 + t) * NBANDS + c]);
    }

    // ---- top-11 + margin flag + approx outputs ----
    if (tid < TOK) {
        int t = tid;
        float* lv = lvalf + t * 11;
        int*   li = lidx + t * 11;
        #pragma unroll
        for (int k = 0; k < 11; ++k) { lv[k] = -3.0e38f; li[k] = 0; }
        for (int c = 0; c < NBANDS; ++c) {
            float v = hf[t * HSF + c] * sigsf[c];
            if (v > lv[10]) {
                int j = 10;
                while (j > 0 && lv[j - 1] < v) {
                    lv[j] = lv[j - 1]; li[j] = li[j - 1]; --j;
                }
                lv[j] = v; li[j] = c;
            }
        }
        float margin = lv[9] - lv[10];
        if (margin < TAU) {
            int slot = atomicAdd(cnt, 1);
            if (slot < LISTCAP) list[slot] = p0 + t;
        }
        for (int a = 1; a < KSEL; ++a) {      // sort top-10 by band index
            float v = lv[a]; int ci = li[a];
            int bq = a - 1;
            while (bq >= 0 && li[bq] > ci) {
                lv[bq + 1] = lv[bq]; li[bq + 1] = li[bq]; --bq;
            }
            lv[bq + 1] = v; li[bq + 1] = ci;
        }
        float sel[KSEL];
        #pragma unroll
        for (int k = 0; k < KSEL; ++k) {
            int ci = li[k];
            float band = __builtin_nontemporal_load(&xo[(size_t)ci * NPIX + p0 + t]);
            __builtin_nontemporal_store((float)ci, &out[IDX_OFF + (size_t)(p0 + t) * KSEL + k]);
            __builtin_nontemporal_store(band, &out[SEL_OFF + (size_t)(p0 + t) * KSEL + k]);
            sel[k] = band * lv[k];
        }
        float e1[8], e2[8];
        #pragma unroll
        for (int e = 0; e < 8; ++e) {
            float acc = be1[e];
            #pragma unroll
            for (int k = 0; k < KSEL; ++k) acc += sel[k] * We1[e * KSEL + k];
            e1[e] = acc > 0.f ? acc : 0.f;
        }
        #pragma unroll
        for (int e = 0; e < 8; ++e) {
            float acc = be2[e];
            #pragma unroll
            for (int j = 0; j < 8; ++j) acc += e1[j] * We2[e * 8 + j];
            e2[e] = acc;
        }
        #pragma unroll
        for (int e = 0; e < 8; ++e) {
            float acc = bd1[e];
            #pragma unroll
            for (int j = 0; j < 8; ++j) acc += e2[j] * Wd1[e * 8 + j];
            d1sf[t * 9 + e] = acc > 0.f ? acc : 0.f;
        }
    }
    __syncthreads();

    for (int idx = tid; idx < TOK * NBANDS; idx += 512) {
        int t = idx & 15, c = idx >> 4;
        float acc = bd2[c];
        const float* w = Wd2 + c * 8;
        #pragma unroll
        for (int e = 0; e < 8; ++e) acc += d1sf[t * 9 + e] * w[e];
        __builtin_nontemporal_store(acc, &out[REC_OFF + (size_t)c * NPIX + p0 + t]);
    }
}

// ---------------- repair kernel (exact fp64 MFMA, token-list; r12-proven) ----------------

__device__ inline void layer_norm_inplace(double* __restrict__ h, double* __restrict__ red,
                                          const float* __restrict__ w, const float* __restrict__ b,
                                          int tid) {
    {
        int t = tid >> 5, q = tid & 31;
        double s = 0.0, ss = 0.0;
        for (int j = q; j < NBANDS; j += 32) {
            double v = h[t * HS + j]; s += v; ss += v * v;
        }
        #pragma unroll
        for (int m = 1; m < 32; m <<= 1) {
            s  += __shfl_xor(s, m, 64);
            ss += __shfl_xor(ss, m, 64);
        }
        if (q == 0) { red[t * 2] = s; red[t * 2 + 1] = ss; }
    }
    __syncthreads();
    for (int idx = tid; idx < TOK * NBANDS; idx += 512) {
        int t = idx / NBANDS, j = idx - t * NBANDS;
        double mu  = red[t * 2] / 400.0;
        double var = red[t * 2 + 1] / 400.0 - mu * mu;
        double rs  = 1.0 / sqrt(var + 1e-5);
        h[t * HS + j] = (h[t * HS + j] - mu) * rs * (double)w[j] + (double)b[j];
    }
    __syncthreads();
}

__global__ __launch_bounds__(512) void hbsm_repair(
    const float* __restrict__ x, const float* __restrict__ xo,
    const float* __restrict__ pos,
    const float* __restrict__ ln1w, const float* __restrict__ ln1b,
    const float* __restrict__ b1,   const float* __restrict__ b2,
    const float* __restrict__ ln2w, const float* __restrict__ ln2b,
    const float* __restrict__ We1,  const float* __restrict__ be1,
    const float* __restrict__ We2,  const float* __restrict__ be2,
    const float* __restrict__ Wd1,  const float* __restrict__ bd1,
    const float* __restrict__ Wd2,  const float* __restrict__ bd2,
    const double* __restrict__ WvoT, const double* __restrict__ bvo,
    const double* __restrict__ sigd,
    const float* __restrict__ W1Tf,  const float* __restrict__ W2Tf,
    const int* __restrict__ cnt, const int* __restrict__ list,
    float* __restrict__ out)
{
    const int n = *cnt;
    if ((int)blockIdx.x * TOK >= n) return;

    extern __shared__ double smem[];
    double* h    = smem;
    double* f    = h + TOK * HS;
    double* red  = f + TOK * FS;
    double* lval = red + 64;
    double* sigs = lval + 160;
    float*  d1s  = (float*)(sigs + 400);
    int*    lidx = (int*)(d1s + 144);
    int*    ptok = (int*)(lidx + 160);

    const int tid  = threadIdx.x;
    const int lane = tid & 63;
    const int wv   = tid >> 6;
    const int rA   = lane & 15;
    const int kq   = lane >> 4;

    if (tid < TOK) {
        int slot = blockIdx.x * TOK + tid;
        ptok[tid] = (slot < n && slot < LISTCAP) ? list[slot] : -1;
    }

    int rowm[4], colm[4];
    {
        f64x4 z = {0.0, 0.0, 0.0, 0.0};
        f64x4 pr = MFMA64(0.25 * (double)rA, 1.0, z);
        f64x4 pc = MFMA64(0.25, (double)rA, z);
        #pragma unroll
        for (int i = 0; i < 4; ++i) {
            rowm[i] = ((int)(pr[i] + 0.5)) & 15;
            colm[i] = ((int)(pc[i] + 0.5)) & 15;
        }
    }

    for (int i = tid; i < NBANDS; i += 512) sigs[i] = sigd[i];
    __syncthreads();
    for (int i = tid; i < TOK * NBANDS; i += 512) {
        int t = i & 15, c = i >> 4;
        int pt = ptok[t];
        h[t * HS + c] = (pt >= 0) ? ((double)x[(size_t)c * NPIX + pt] + (double)pos[c]) : 0.0;
    }
    __syncthreads();

    const double* hA = h + rA * HS;
    const int c0 = wv * 16 + rA, c1 = c0 + 128, c2 = c0 + 256;
    const int ct = 384 + rA;
    const bool xtraA = (wv == 0);
    const bool xtraF = (wv == 4);

    for (int l = 0; l < 2; ++l) {
        {
            const double* WT  = WvoT + l * 160000;
            const double* bb0 = bvo + l * 400;
            f64x4 a0={0,0,0,0}, a1={0,0,0,0}, a2={0,0,0,0}, a3={0,0,0,0};
            #pragma unroll 2
            for (int k0 = 0; k0 < NBANDS; k0 += 4) {
                double av = hA[k0 + kq];
                const double* wrow = WT + (size_t)(k0 + kq) * 400;
                a0 = MFMA64(av, wrow[c0], a0);
                a1 = MFMA64(av, wrow[c1], a1);
                a2 = MFMA64(av, wrow[c2], a2);
                if (xtraA) a3 = MFMA64(av, wrow[ct], a3);
            }
            __syncthreads();
            #pragma unroll
            for (int i = 0; i < 4; ++i) {
                int r  = rowm[i];
                int j0 = wv * 16 + colm[i], j1 = j0 + 128, j2 = j0 + 256;
                h[r * HS + j0] += a0[i] + bb0[j0];
                h[r * HS + j1] += a1[i] + bb0[j1];
                h[r * HS + j2] += a2[i] + bb0[j2];
                if (xtraA) {
                    int jtl = 384 + colm[i];
                    h[r * HS + jtl] += a3[i] + bb0[jtl];
                }
            }
            __syncthreads();
        }
        layer_norm_inplace(h, red, ln1w + l * 400, ln1b + l * 400, tid);

        {
            const float* WT  = W1Tf + (size_t)l * 51200;
            const float* bb1 = b1 + l * FFW;
            const int cf = wv * 16 + rA;
            f64x4 e0 = {0,0,0,0};
            #pragma unroll 2
            for (int k0 = 0; k0 < NBANDS; k0 += 4) {
                double av = hA[k0 + kq];
                double b = (double)WT[(size_t)(k0 + kq) * FFW + cf];
                e0 = MFMA64(av, b, e0);
            }
            #pragma unroll
            for (int i = 0; i < 4; ++i) {
                int r  = rowm[i];
                int jf = wv * 16 + colm[i];
                double v0 = e0[i] + (double)bb1[jf];
                f[r * FS + jf] = v0 > 0.0 ? v0 : 0.0;
            }
            __syncthreads();
        }

        {
            const float* WT  = W2Tf + (size_t)l * 51200;
            const float* bb2 = b2 + l * 400;
            const double* fA = f + rA * FS;
            f64x4 a0={0,0,0,0}, a1={0,0,0,0}, a2={0,0,0,0}, a3={0,0,0,0};
            #pragma unroll 2
            for (int k0 = 0; k0 < FFW; k0 += 4) {
                double av = fA[k0 + kq];
                const float* wrow = WT + (size_t)(k0 + kq) * 400;
                a0 = MFMA64(av, (double)wrow[c0], a0);
                a1 = MFMA64(av, (double)wrow[c1], a1);
                a2 = MFMA64(av, (double)wrow[c2], a2);
                if (xtraF) a3 = MFMA64(av, (double)wrow[ct], a3);
            }
            #pragma unroll
            for (int i = 0; i < 4; ++i) {
                int r  = rowm[i];
                int j0 = wv * 16 + colm[i], j1 = j0 + 128, j2 = j0 + 256;
                h[r * HS + j0] += a0[i] + (double)bb2[j0];
                h[r * HS + j1] += a1[i] + (double)bb2[j1];
                h[r * HS + j2] += a2[i] + (double)bb2[j2];
                if (xtraF) {
                    int jtl = 384 + colm[i];
                    h[r * HS + jtl] += a3[i] + (double)bb2[jtl];
                }
            }
            __syncthreads();
        }
        layer_norm_inplace(h, red, ln2w + l * 400, ln2b + l * 400, tid);
    }

    for (int idx = tid; idx < TOK * NBANDS; idx += 512) {
        int t = idx / NBANDS, c = idx - t * NBANDS;
        if (ptok[t] >= 0)
            out[SCO_OFF + (size_t)ptok[t] * NBANDS + c] = (float)(h[t * HS + c] * sigs[c]);
    }

    if (tid < TOK && ptok[tid] >= 0) {
        int t = tid, pt = ptok[t];
        double* lv = lval + t * KSEL;
        int*    li = lidx + t * KSEL;
        #pragma unroll
        for (int k = 0; k < KSEL; ++k) { lv[k] = -1.0e300; li[k] = 0; }
        for (int c = 0; c < NBANDS; ++c) {
            double v = h[t * HS + c] * sigs[c];
            if (v > lv[KSEL - 1]) {
                int j = KSEL - 1;
                while (j > 0 && lv[j - 1] < v) {
                    lv[j] = lv[j - 1]; li[j] = li[j - 1]; --j;
                }
                lv[j] = v; li[j] = c;
            }
        }
        for (int a = 1; a < KSEL; ++a) {
            double v = lv[a]; int ci = li[a];
            int bq = a - 1;
            while (bq >= 0 && li[bq] > ci) {
                lv[bq + 1] = lv[bq]; li[bq + 1] = li[bq]; --bq;
            }
            lv[bq + 1] = v; li[bq + 1] = ci;
        }
        double sel[KSEL];
        #pragma unroll
        for (int k = 0; k < KSEL; ++k) {
            int ci = li[k];
            float band = xo[(size_t)ci * NPIX + pt];
            out[IDX_OFF + (size_t)pt * KSEL + k] = (float)ci;
            out[SEL_OFF + (size_t)pt * KSEL + k] = band;
            sel[k] = (double)band * lv[k];
        }
        double e1[8], e2[8];
        #pragma unroll
        for (int e = 0; e < 8; ++e) {
            double acc = (double)be1[e];
            #pragma unroll
            for (int k = 0; k < KSEL; ++k) acc += sel[k] * (double)We1[e * KSEL + k];
            e1[e] = acc > 0.0 ? acc : 0.0;
        }
        #pragma unroll
        for (int e = 0; e < 8; ++e) {
            double acc = (double)be2[e];
            #pragma unroll
            for (int j = 0; j < 8; ++j) acc += e1[j] * (double)We2[e * 8 + j];
            e2[e] = acc;
        }
        #pragma unroll
        for (int e = 0; e < 8; ++e) {
            double acc = (double)bd1[e];
            #pragma unroll
            for (int j = 0; j < 8; ++j) acc += e2[j] * (double)Wd1[e * 8 + j];
            d1s[t * 9 + e] = (float)(acc > 0.0 ? acc : 0.0);
        }
    }
    __syncthreads();

    for (int idx = tid; idx < TOK * NBANDS; idx += 512) {
        int t = idx & 15, c = idx >> 4;
        if (ptok[t] < 0) continue;
        double acc = (double)bd2[c];
        const float* w = Wd2 + c * 8;
        #pragma unroll
        for (int e = 0; e < 8; ++e) acc += (double)d1s[t * 9 + e] * (double)w[e];
        out[REC_OFF + (size_t)c * NPIX + ptok[t]] = (float)acc;
    }
}

// ---------------- launch ----------------
extern "C" void kernel_launch(void* const* d_in, const int* in_sizes, int n_in,
                              void* d_out, int out_size, void* d_ws, size_t ws_size,
                              hipStream_t stream) {
    if (ws_size < WS_NEED) {
        sentinel_kernel<<<dim3(256), dim3(256), 0, stream>>>((float*)d_out, -777.0f);
        return;
    }
    if (out_size != OUT_EXPECT) {
        sentinel_kernel<<<dim3(1), dim3(1), 0, stream>>>((float*)d_out, 1.0e6f);
        return;
    }
    const float* x    = (const float*)d_in[0];
    const float* xo   = (const float*)d_in[1];
    const float* pos  = (const float*)d_in[2];
    const float* bi   = (const float*)d_in[3];
    const float* Wv   = (const float*)d_in[4];
    const float* bv   = (const float*)d_in[5];
    const float* Wo   = (const float*)d_in[6];
    const float* bo   = (const float*)d_in[7];
    const float* ln1w = (const float*)d_in[8];
    const float* ln1b = (const float*)d_in[9];
    const float* W1   = (const float*)d_in[10];
    const float* b1   = (const float*)d_in[11];
    const float* W2   = (const float*)d_in[12];
    const float* b2   = (const float*)d_in[13];
    const float* ln2w = (const float*)d_in[14];
    const float* ln2b = (const float*)d_in[15];
    const float* We1  = (const float*)d_in[16];
    const float* be1  = (const float*)d_in[17];
    const float* We2  = (const float*)d_in[18];
    const float* be2  = (const float*)d_in[19];
    const float* Wd1  = (const float*)d_in[20];
    const float* bd1  = (const float*)d_in[21];
    const float* Wd2  = (const float*)d_in[22];
    const float* bd2  = (const float*)d_in[23];

    char* wsb = (char*)d_ws;
    double* WvoT = (double*)(wsb + WSB_WVOT);
    double* bvo  = (double*)(wsb + WSB_BVO);
    double* sigd = (double*)(wsb + WSB_SIG);
    float*  W1Tf = (float*)(wsb + WSB_W1T);
    float*  W2Tf = (float*)(wsb + WSB_W2T);
    float*  WvoP = (float*)(wsb + WSB_WVP);
    float*  W2P  = (float*)(wsb + WSB_W2P);
    int*    cnt  = (int*)(wsb + WSB_CNT);
    int*    list = (int*)(wsb + WSB_LIST);

    zero_cnt<<<dim3(1), dim3(64), 0, stream>>>(cnt);
    prep_wvot<<<dim3(800), dim3(512), 0, stream>>>(Wv, Wo, WvoT);
    prep_transpose<<<dim3(400), dim3(256), 0, stream>>>(W1, W2, W1Tf, W2Tf);
    prep_padf<<<dim3(800), dim3(512), 0, stream>>>(WvoT, W2Tf, WvoP, W2P);
    prep_small<<<dim3(5), dim3(256), 0, stream>>>(Wo, bv, bo, bi, bvo, sigd);

    const int smem_fast = 38016;
    hipFuncSetAttribute((const void*)hbsm_fast,
                        hipFuncAttributeMaxDynamicSharedMemorySize, smem_fast);
    hipLaunchKernelGGL(hbsm_fast, dim3(4096), dim3(512), smem_fast, stream,
                       x, xo, pos, ln1w, ln1b, b1, b2, ln2w, ln2b,
                       We1, be1, We2, be2, Wd1, bd1, Wd2, bd2,
                       bvo, sigd, WvoP, W1Tf, W2P, cnt, list, (float*)d_out);

    const int smem_rep = 74624;
    hipFuncSetAttribute((const void*)hbsm_repair,
                        hipFuncAttributeMaxDynamicSharedMemorySize, smem_rep);
    hipLaunchKernelGGL(hbsm_repair, dim3(1024), dim3(512), smem_rep, stream,
                       x, xo, pos, ln1w, ln1b, b1, b2, ln2w, ln2b,
                       We1, be1, We2, be2, Wd1, bd1, Wd2, bd2,
                       WvoT, bvo, sigd, W1Tf, W2Tf, cnt, list, (float*)d_out);
    (void)in_sizes; (void)n_in;
}

// Round 15
// 2309.132 us; speedup vs baseline: 1.4083x; 1.1545x over previous
//
#include <hip/hip_runtime.h>
#include <hip/hip_bf16.h>
#include <math.h>

#define NBANDS 400
#define NPIX   65536
#define FFW    128
#define KSEL   10
#define TOK    16     // repair tokens/WG
#define TOKF   32     // fast tokens/WG
#define HS     403    // repair h stride (f64)
#define FS     131    // repair f stride (f64)
#define HSF    404    // fast h stride (f32)
#define FSF    132    // fast f stride (f32)
#define WPAD   512    // padded weight row (f32)
#define TAU    1e-3f
#define LISTCAP 16384

typedef double f64x4 __attribute__((ext_vector_type(4)));
typedef float  f32x4 __attribute__((ext_vector_type(4)));
#define MFMA64(a,b,c) __builtin_amdgcn_mfma_f64_16x16x4f64((a),(b),(c),0,0,0)

// ---- ws byte offsets ----
static constexpr size_t WSB_WVOT = 0;          // f64 [2][400][400] WvoT[l][k][j]=(Wo@Wv)[j][k]
static constexpr size_t WSB_BVO  = 2560000;    // f64 [2][400]
static constexpr size_t WSB_SIG  = 2566400;    // f64 [400]
static constexpr size_t WSB_W1T  = 2569600;    // f32 [2][400][128]
static constexpr size_t WSB_W2T  = 2979200;    // f32 [2][128][400]
static constexpr size_t WSB_WVP  = 3388800;    // f32 [2][400][512] zero-padded
static constexpr size_t WSB_W2P  = 5027200;    // f32 [2][128][512] zero-padded
static constexpr size_t WSB_CNT  = 5551488;    // int counter
static constexpr size_t WSB_LIST = 5551552;    // int [16384]
static constexpr size_t WS_NEED  = 5617088;

// ---- out offsets (fp32 elements) ----
static constexpr size_t REC_OFF = 0;
static constexpr size_t IDX_OFF = 26214400;
static constexpr size_t SCO_OFF = IDX_OFF + 655360;
static constexpr size_t SEL_OFF = SCO_OFF + 26214400;
static constexpr int    OUT_EXPECT = 53739520;

// ---------------- prep kernels ----------------

__global__ void prep_wvot(const float* __restrict__ Wv, const float* __restrict__ Wo,
                          double* __restrict__ WvoT) {
    int b = blockIdx.x;
    int l = b / 400, j = b - l * 400;
    int k = threadIdx.x;
    if (k >= 400) return;
    const float* wo = Wo + l * 160000 + j * 400;
    const float* wv = Wv + l * 160000;
    double acc = 0.0;
    #pragma unroll 4
    for (int m = 0; m < 400; ++m)
        acc += (double)wo[m] * (double)wv[m * 400 + k];
    WvoT[l * 160000 + k * 400 + j] = acc;
}

__global__ void prep_transpose(const float* __restrict__ W1, const float* __restrict__ W2,
                               float* __restrict__ W1T, float* __restrict__ W2T) {
    int idx = blockIdx.x * blockDim.x + threadIdx.x;
    if (idx < 2 * FFW * NBANDS) {
        int l = idx / (FFW * NBANDS); int r = idx - l * (FFW * NBANDS);
        int jf = r / NBANDS; int k = r - jf * NBANDS;
        W1T[l * FFW * NBANDS + k * FFW + jf] = W1[idx];
        int j = r / FFW; int kf = r - j * FFW;
        W2T[l * FFW * NBANDS + kf * NBANDS + j] = W2[idx];
    }
}

// zero-padded fp32 copies: WvoP [2][400][512], W2P [2][128][512]
__global__ void prep_padf(const double* __restrict__ WvoT, const float* __restrict__ W2T,
                          float* __restrict__ WvoP, float* __restrict__ W2P) {
    int i = blockIdx.x * blockDim.x + threadIdx.x;
    if (i < 2 * 400 * WPAD) {
        int l = i / (400 * WPAD), r = i % (400 * WPAD), k = r / WPAD, c = r % WPAD;
        WvoP[i] = (c < 400) ? (float)WvoT[(size_t)l * 160000 + (size_t)k * 400 + c] : 0.f;
    }
    if (i < 2 * FFW * WPAD) {
        int l = i / (FFW * WPAD), r = i % (FFW * WPAD), k = r / WPAD, c = r % WPAD;
        W2P[i] = (c < 400) ? W2T[(size_t)l * 51200 + (size_t)k * 400 + c] : 0.f;
    }
}

__global__ void prep_small(const float* __restrict__ Wo, const float* __restrict__ bv,
                           const float* __restrict__ bo, const float* __restrict__ bi,
                           double* __restrict__ bvo, double* __restrict__ sigd) {
    int g = blockIdx.x * blockDim.x + threadIdx.x;
    if (g < 800) {
        int l = g / 400;
        const float* wo = Wo + l * 160000 + (g - l * 400) * 400;
        const float* bb = bv + l * 400;
        double acc = (double)bo[g];
        for (int m = 0; m < 400; ++m) acc += (double)wo[m] * (double)bb[m];
        bvo[g] = acc;
    } else if (g < 1200) {
        int c = g - 800;
        sigd[c] = 1.0 / (1.0 + exp(-(double)bi[c]));
    }
}

__global__ void zero_cnt(int* cnt) { if (threadIdx.x == 0) *cnt = 0; }

__global__ void sentinel_kernel(float* out, float v) {
    out[blockIdx.x * 256 + threadIdx.x] = v;
}

// ---------------- main (fast, fp32 VALU) kernel ----------------
// 32 tokens/WG, 512 threads = 8 waves; LDS 74432 B -> 2 WGs/CU.
// GEMM map (attn/FF2): tg=tid>>7 -> TM=8 tokens; cx=tid&127, jb=cx*4 -> TN=4
// float4 cols from 512-padded weights (cx<100 active; no tail path).
// 128 FMA per 4 VMEM loads per k4 (2x r14's density); per-token weight
// traffic halved. Margin<TAU tokens repaired exactly in fp64 (r12-proven).

__device__ inline void ln_f32(float* __restrict__ hf, float* __restrict__ redf,
                              const float* __restrict__ w, const float* __restrict__ b, int tid) {
    {
        int t = tid >> 4, q = tid & 15;       // 32 tokens x 16 lanes
        float s = 0.f, ss = 0.f;
        for (int j = q; j < NBANDS; j += 16) {
            float v = hf[t * HSF + j]; s += v; ss += v * v;
        }
        #pragma unroll
        for (int m = 1; m < 16; m <<= 1) {
            s  += __shfl_xor(s, m, 64);
            ss += __shfl_xor(ss, m, 64);
        }
        if (q == 0) { redf[t * 2] = s; redf[t * 2 + 1] = ss; }
    }
    __syncthreads();
    for (int idx = tid; idx < TOKF * NBANDS; idx += 512) {
        int t = idx / NBANDS, j = idx - t * NBANDS;
        float mu  = redf[t * 2] * (1.0f / 400.0f);
        float var = redf[t * 2 + 1] * (1.0f / 400.0f) - mu * mu;
        float rs  = 1.0f / sqrtf(var + 1e-5f);
        hf[t * HSF + j] = (hf[t * HSF + j] - mu) * rs * w[j] + b[j];
    }
    __syncthreads();
}

__global__ __launch_bounds__(512, 4) void hbsm_fast(
    const float* __restrict__ x, const float* __restrict__ xo,
    const float* __restrict__ pos,
    const float* __restrict__ ln1w, const float* __restrict__ ln1b,
    const float* __restrict__ b1,   const float* __restrict__ b2,
    const float* __restrict__ ln2w, const float* __restrict__ ln2b,
    const float* __restrict__ We1,  const float* __restrict__ be1,
    const float* __restrict__ We2,  const float* __restrict__ be2,
    const float* __restrict__ Wd1,  const float* __restrict__ bd1,
    const float* __restrict__ Wd2,  const float* __restrict__ bd2,
    const double* __restrict__ bvo, const double* __restrict__ sigd,
    const float* __restrict__ WvoP, const float* __restrict__ W1Tf,
    const float* __restrict__ W2P,
    int* __restrict__ cnt, int* __restrict__ list,
    float* __restrict__ out)
{
    extern __shared__ char smemc[];
    float* hf    = (float*)smemc;                 // 32*404          (51712 B)
    float* ff    = (float*)(smemc + 51712);       // 32*132          (16896 B)
    float* sigsf = (float*)(smemc + 68608);       // 400
    float* redf  = (float*)(smemc + 70208);       // 64
    float* lvalf = (float*)(smemc + 70464);       // 32*11
    int*   lidx  = (int*)(smemc + 71872);         // 32*11
    float* d1sf  = (float*)(smemc + 73280);       // 32*9  -> end 74432

    const int tid = threadIdx.x;
    const int p0  = blockIdx.x * TOKF;

    for (int i = tid; i < NBANDS; i += 512) sigsf[i] = (float)sigd[i];
    for (int i = tid; i < TOKF * NBANDS; i += 512) {
        int t = i & 31, c = i >> 5;
        float xv = __builtin_nontemporal_load(&x[(size_t)c * NPIX + p0 + t]);
        hf[t * HSF + c] = xv + pos[c];
    }
    __syncthreads();

    const int tg = tid >> 7;              // 0..3, wave-uniform
    const int cx = tid & 127;
    const int t0 = tg * 8;
    const int jb = cx * 4;                // 0..508
    const bool cw = (jb < NBANDS);        // cx < 100

    for (int l = 0; l < 2; ++l) {
        // ---- attention: hf += h @ Wvo^T + bvo ; LN1 ----
        {
            const float* WT = WvoP + (size_t)l * 400 * WPAD;
            f32x4 acc[8];
            #pragma unroll
            for (int i = 0; i < 8; ++i) acc[i] = (f32x4){0,0,0,0};
            #pragma unroll 2
            for (int k4 = 0; k4 < NBANDS; k4 += 4) {
                f32x4 av[8];
                #pragma unroll
                for (int i = 0; i < 8; ++i)
                    av[i] = *(const f32x4*)&hf[(t0 + i) * HSF + k4];
                #pragma unroll
                for (int kk = 0; kk < 4; ++kk) {
                    f32x4 w = *(const f32x4*)&WT[(size_t)(k4 + kk) * WPAD + jb];
                    #pragma unroll
                    for (int i = 0; i < 8; ++i) acc[i] += av[i][kk] * w;
                }
            }
            __syncthreads();   // all reads of hf done before in-place update
            if (cw) {
                #pragma unroll
                for (int n = 0; n < 4; ++n) {
                    float bvn = (float)bvo[l * 400 + jb + n];
                    #pragma unroll
                    for (int i = 0; i < 8; ++i)
                        hf[(t0 + i) * HSF + jb + n] += acc[i][n] + bvn;
                }
            }
            __syncthreads();
        }
        ln_f32(hf, redf, ln1w + l * 400, ln1b + l * 400, tid);

        // ---- FF1: ff = relu(h @ W1^T + b1) ; col jf = cx ----
        {
            const float* WT = W1Tf + (size_t)l * 51200;
            const int jf = cx;
            float acc1[8];
            #pragma unroll
            for (int i = 0; i < 8; ++i) acc1[i] = 0.f;
            #pragma unroll 2
            for (int k4 = 0; k4 < NBANDS; k4 += 4) {
                f32x4 av[8];
                #pragma unroll
                for (int i = 0; i < 8; ++i)
                    av[i] = *(const f32x4*)&hf[(t0 + i) * HSF + k4];
                #pragma unroll
                for (int kk = 0; kk < 4; ++kk) {
                    float w = WT[(size_t)(k4 + kk) * FFW + jf];
                    #pragma unroll
                    for (int i = 0; i < 8; ++i) acc1[i] += av[i][kk] * w;
                }
            }
            float bias = b1[l * FFW + jf];
            #pragma unroll
            for (int i = 0; i < 8; ++i) {
                float v = acc1[i] + bias;
                ff[(t0 + i) * FSF + jf] = v > 0.f ? v : 0.f;
            }
            __syncthreads();   // ff visible (also fences FF1's hf reads)
        }

        // ---- FF2: hf += f @ W2^T + b2 ; LN2 ----
        {
            const float* WT = W2P + (size_t)l * FFW * WPAD;
            f32x4 acc[8];
            #pragma unroll
            for (int i = 0; i < 8; ++i) acc[i] = (f32x4){0,0,0,0};
            #pragma unroll 2
            for (int k4 = 0; k4 < FFW; k4 += 4) {
                f32x4 av[8];
                #pragma unroll
                for (int i = 0; i < 8; ++i)
                    av[i] = *(const f32x4*)&ff[(t0 + i) * FSF + k4];
                #pragma unroll
                for (int kk = 0; kk < 4; ++kk) {
                    f32x4 w = *(const f32x4*)&WT[(size_t)(k4 + kk) * WPAD + jb];
                    #pragma unroll
                    for (int i = 0; i < 8; ++i) acc[i] += av[i][kk] * w;
                }
            }
            // only ff is read; hf writes owner-disjoint
            if (cw) {
                #pragma unroll
                for (int n = 0; n < 4; ++n) {
                    float bvn = b2[l * 400 + jb + n];
                    #pragma unroll
                    for (int i = 0; i < 8; ++i)
                        hf[(t0 + i) * HSF + jb + n] += acc[i][n] + bvn;
                }
            }
            __syncthreads();
        }
        ln_f32(hf, redf, ln2w + l * 400, ln2b + l * 400, tid);
    }

    // ---- scores output ----
    for (int idx = tid; idx < TOKF * NBANDS; idx += 512) {
        int t = idx / NBANDS, c = idx - t * NBANDS;
        __builtin_nontemporal_store(hf[t * HSF + c] * sigsf[c],
                                    &out[SCO_OFF + (size_t)(p0 + t) * NBANDS + c]);
    }

    // ---- top-11 + margin flag + approx outputs ----
    if (tid < TOKF) {
        int t = tid;
        float* lv = lvalf + t * 11;
        int*   li = lidx + t * 11;
        #pragma unroll
        for (int k = 0; k < 11; ++k) { lv[k] = -3.0e38f; li[k] = 0; }
        for (int c = 0; c < NBANDS; ++c) {
            float v = hf[t * HSF + c] * sigsf[c];
            if (v > lv[10]) {
                int j = 10;
                while (j > 0 && lv[j - 1] < v) {
                    lv[j] = lv[j - 1]; li[j] = li[j - 1]; --j;
                }
                lv[j] = v; li[j] = c;
            }
        }
        float margin = lv[9] - lv[10];
        if (margin < TAU) {
            int slot = atomicAdd(cnt, 1);
            if (slot < LISTCAP) list[slot] = p0 + t;
        }
        for (int a = 1; a < KSEL; ++a) {      // sort top-10 by band index
            float v = lv[a]; int ci = li[a];
            int bq = a - 1;
            while (bq >= 0 && li[bq] > ci) {
                lv[bq + 1] = lv[bq]; li[bq + 1] = li[bq]; --bq;
            }
            lv[bq + 1] = v; li[bq + 1] = ci;
        }
        float sel[KSEL];
        #pragma unroll
        for (int k = 0; k < KSEL; ++k) {
            int ci = li[k];
            float band = __builtin_nontemporal_load(&xo[(size_t)ci * NPIX + p0 + t]);
            __builtin_nontemporal_store((float)ci, &out[IDX_OFF + (size_t)(p0 + t) * KSEL + k]);
            __builtin_nontemporal_store(band, &out[SEL_OFF + (size_t)(p0 + t) * KSEL + k]);
            sel[k] = band * lv[k];
        }
        float e1[8], e2[8];
        #pragma unroll
        for (int e = 0; e < 8; ++e) {
            float acc = be1[e];
            #pragma unroll
            for (int k = 0; k < KSEL; ++k) acc += sel[k] * We1[e * KSEL + k];
            e1[e] = acc > 0.f ? acc : 0.f;
        }
        #pragma unroll
        for (int e = 0; e < 8; ++e) {
            float acc = be2[e];
            #pragma unroll
            for (int j = 0; j < 8; ++j) acc += e1[j] * We2[e * 8 + j];
            e2[e] = acc;
        }
        #pragma unroll
        for (int e = 0; e < 8; ++e) {
            float acc = bd1[e];
            #pragma unroll
            for (int j = 0; j < 8; ++j) acc += e2[j] * Wd1[e * 8 + j];
            d1sf[t * 9 + e] = acc > 0.f ? acc : 0.f;
        }
    }
    __syncthreads();

    for (int idx = tid; idx < TOKF * NBANDS; idx += 512) {
        int t = idx & 31, c = idx >> 5;
        float acc = bd2[c];
        const float* w = Wd2 + c * 8;
        #pragma unroll
        for (int e = 0; e < 8; ++e) acc += d1sf[t * 9 + e] * w[e];
        __builtin_nontemporal_store(acc, &out[REC_OFF + (size_t)c * NPIX + p0 + t]);
    }
}

// ---------------- repair kernel (exact fp64 MFMA, token-list; r12-proven) ----------------

__device__ inline void layer_norm_inplace(double* __restrict__ h, double* __restrict__ red,
                                          const float* __restrict__ w, const float* __restrict__ b,
                                          int tid) {
    {
        int t = tid >> 5, q = tid & 31;
        double s = 0.0, ss = 0.0;
        for (int j = q; j < NBANDS; j += 32) {
            double v = h[t * HS + j]; s += v; ss += v * v;
        }
        #pragma unroll
        for (int m = 1; m < 32; m <<= 1) {
            s  += __shfl_xor(s, m, 64);
            ss += __shfl_xor(ss, m, 64);
        }
        if (q == 0) { red[t * 2] = s; red[t * 2 + 1] = ss; }
    }
    __syncthreads();
    for (int idx = tid; idx < TOK * NBANDS; idx += 512) {
        int t = idx / NBANDS, j = idx - t * NBANDS;
        double mu  = red[t * 2] / 400.0;
        double var = red[t * 2 + 1] / 400.0 - mu * mu;
        double rs  = 1.0 / sqrt(var + 1e-5);
        h[t * HS + j] = (h[t * HS + j] - mu) * rs * (double)w[j] + (double)b[j];
    }
    __syncthreads();
}

__global__ __launch_bounds__(512) void hbsm_repair(
    const float* __restrict__ x, const float* __restrict__ xo,
    const float* __restrict__ pos,
    const float* __restrict__ ln1w, const float* __restrict__ ln1b,
    const float* __restrict__ b1,   const float* __restrict__ b2,
    const float* __restrict__ ln2w, const float* __restrict__ ln2b,
    const float* __restrict__ We1,  const float* __restrict__ be1,
    const float* __restrict__ We2,  const float* __restrict__ be2,
    const float* __restrict__ Wd1,  const float* __restrict__ bd1,
    const float* __restrict__ Wd2,  const float* __restrict__ bd2,
    const double* __restrict__ WvoT, const double* __restrict__ bvo,
    const double* __restrict__ sigd,
    const float* __restrict__ W1Tf,  const float* __restrict__ W2Tf,
    const int* __restrict__ cnt, const int* __restrict__ list,
    float* __restrict__ out)
{
    const int n = *cnt;
    if ((int)blockIdx.x * TOK >= n) return;

    extern __shared__ double smem[];
    double* h    = smem;
    double* f    = h + TOK * HS;
    double* red  = f + TOK * FS;
    double* lval = red + 64;
    double* sigs = lval + 160;
    float*  d1s  = (float*)(sigs + 400);
    int*    lidx = (int*)(d1s + 144);
    int*    ptok = (int*)(lidx + 160);

    const int tid  = threadIdx.x;
    const int lane = tid & 63;
    const int wv   = tid >> 6;
    const int rA   = lane & 15;
    const int kq   = lane >> 4;

    if (tid < TOK) {
        int slot = blockIdx.x * TOK + tid;
        ptok[tid] = (slot < n && slot < LISTCAP) ? list[slot] : -1;
    }

    int rowm[4], colm[4];
    {
        f64x4 z = {0.0, 0.0, 0.0, 0.0};
        f64x4 pr = MFMA64(0.25 * (double)rA, 1.0, z);
        f64x4 pc = MFMA64(0.25, (double)rA, z);
        #pragma unroll
        for (int i = 0; i < 4; ++i) {
            rowm[i] = ((int)(pr[i] + 0.5)) & 15;
            colm[i] = ((int)(pc[i] + 0.5)) & 15;
        }
    }

    for (int i = tid; i < NBANDS; i += 512) sigs[i] = sigd[i];
    __syncthreads();
    for (int i = tid; i < TOK * NBANDS; i += 512) {
        int t = i & 15, c = i >> 4;
        int pt = ptok[t];
        h[t * HS + c] = (pt >= 0) ? ((double)x[(size_t)c * NPIX + pt] + (double)pos[c]) : 0.0;
    }
    __syncthreads();

    const double* hA = h + rA * HS;
    const int c0 = wv * 16 + rA, c1 = c0 + 128, c2 = c0 + 256;
    const int ct = 384 + rA;
    const bool xtraA = (wv == 0);
    const bool xtraF = (wv == 4);

    for (int l = 0; l < 2; ++l) {
        {
            const double* WT  = WvoT + l * 160000;
            const double* bb0 = bvo + l * 400;
            f64x4 a0={0,0,0,0}, a1={0,0,0,0}, a2={0,0,0,0}, a3={0,0,0,0};
            #pragma unroll 2
            for (int k0 = 0; k0 < NBANDS; k0 += 4) {
                double av = hA[k0 + kq];
                const double* wrow = WT + (size_t)(k0 + kq) * 400;
                a0 = MFMA64(av, wrow[c0], a0);
                a1 = MFMA64(av, wrow[c1], a1);
                a2 = MFMA64(av, wrow[c2], a2);
                if (xtraA) a3 = MFMA64(av, wrow[ct], a3);
            }
            __syncthreads();
            #pragma unroll
            for (int i = 0; i < 4; ++i) {
                int r  = rowm[i];
                int j0 = wv * 16 + colm[i], j1 = j0 + 128, j2 = j0 + 256;
                h[r * HS + j0] += a0[i] + bb0[j0];
                h[r * HS + j1] += a1[i] + bb0[j1];
                h[r * HS + j2] += a2[i] + bb0[j2];
                if (xtraA) {
                    int jtl = 384 + colm[i];
                    h[r * HS + jtl] += a3[i] + bb0[jtl];
                }
            }
            __syncthreads();
        }
        layer_norm_inplace(h, red, ln1w + l * 400, ln1b + l * 400, tid);

        {
            const float* WT  = W1Tf + (size_t)l * 51200;
            const float* bb1 = b1 + l * FFW;
            const int cf = wv * 16 + rA;
            f64x4 e0 = {0,0,0,0};
            #pragma unroll 2
            for (int k0 = 0; k0 < NBANDS; k0 += 4) {
                double av = hA[k0 + kq];
                double b = (double)WT[(size_t)(k0 + kq) * FFW + cf];
                e0 = MFMA64(av, b, e0);
            }
            #pragma unroll
            for (int i = 0; i < 4; ++i) {
                int r  = rowm[i];
                int jf = wv * 16 + colm[i];
                double v0 = e0[i] + (double)bb1[jf];
                f[r * FS + jf] = v0 > 0.0 ? v0 : 0.0;
            }
            __syncthreads();
        }

        {
            const float* WT  = W2Tf + (size_t)l * 51200;
            const float* bb2 = b2 + l * 400;
            const double* fA = f + rA * FS;
            f64x4 a0={0,0,0,0}, a1={0,0,0,0}, a2={0,0,0,0}, a3={0,0,0,0};
            #pragma unroll 2
            for (int k0 = 0; k0 < FFW; k0 += 4) {
                double av = fA[k0 + kq];
                const float* wrow = WT + (size_t)(k0 + kq) * 400;
                a0 = MFMA64(av, (double)wrow[c0], a0);
                a1 = MFMA64(av, (double)wrow[c1], a1);
                a2 = MFMA64(av, (double)wrow[c2], a2);
                if (xtraF) a3 = MFMA64(av, (double)wrow[ct], a3);
            }
            #pragma unroll
            for (int i = 0; i < 4; ++i) {
                int r  = rowm[i];
                int j0 = wv * 16 + colm[i], j1 = j0 + 128, j2 = j0 + 256;
                h[r * HS + j0] += a0[i] + (double)bb2[j0];
                h[r * HS + j1] += a1[i] + (double)bb2[j1];
                h[r * HS + j2] += a2[i] + (double)bb2[j2];
                if (xtraF) {
                    int jtl = 384 + colm[i];
                    h[r * HS + jtl] += a3[i] + (double)bb2[jtl];
                }
            }
            __syncthreads();
        }
        layer_norm_inplace(h, red, ln2w + l * 400, ln2b + l * 400, tid);
    }

    for (int idx = tid; idx < TOK * NBANDS; idx += 512) {
        int t = idx / NBANDS, c = idx - t * NBANDS;
        if (ptok[t] >= 0)
            out[SCO_OFF + (size_t)ptok[t] * NBANDS + c] = (float)(h[t * HS + c] * sigs[c]);
    }

    if (tid < TOK && ptok[tid] >= 0) {
        int t = tid, pt = ptok[t];
        double* lv = lval + t * KSEL;
        int*    li = lidx + t * KSEL;
        #pragma unroll
        for (int k = 0; k < KSEL; ++k) { lv[k] = -1.0e300; li[k] = 0; }
        for (int c = 0; c < NBANDS; ++c) {
            double v = h[t * HS + c] * sigs[c];
            if (v > lv[KSEL - 1]) {
                int j = KSEL - 1;
                while (j > 0 && lv[j - 1] < v) {
                    lv[j] = lv[j - 1]; li[j] = li[j - 1]; --j;
                }
                lv[j] = v; li[j] = c;
            }
        }
        for (int a = 1; a < KSEL; ++a) {
            double v = lv[a]; int ci = li[a];
            int bq = a - 1;
            while (bq >= 0 && li[bq] > ci) {
                lv[bq + 1] = lv[bq]; li[bq + 1] = li[bq]; --bq;
            }
            lv[bq + 1] = v; li[bq + 1] = ci;
        }
        double sel[KSEL];
        #pragma unroll
        for (int k = 0; k < KSEL; ++k) {
            int ci = li[k];
            float band = xo[(size_t)ci * NPIX + pt];
            out[IDX_OFF + (size_t)pt * KSEL + k] = (float)ci;
            out[SEL_OFF + (size_t)pt * KSEL + k] = band;
            sel[k] = (double)band * lv[k];
        }
        double e1[8], e2[8];
        #pragma unroll
        for (int e = 0; e < 8; ++e) {
            double acc = (double)be1[e];
            #pragma unroll
            for (int k = 0; k < KSEL; ++k) acc += sel[k] * (double)We1[e * KSEL + k];
            e1[e] = acc > 0.0 ? acc : 0.0;
        }
        #pragma unroll
        for (int e = 0; e < 8; ++e) {
            double acc = (double)be2[e];
            #pragma unroll
            for (int j = 0; j < 8; ++j) acc += e1[j] * (double)We2[e * 8 + j];
            e2[e] = acc;
        }
        #pragma unroll
        for (int e = 0; e < 8; ++e) {
            double acc = (double)bd1[e];
            #pragma unroll
            for (int j = 0; j < 8; ++j) acc += e2[j] * (double)Wd1[e * 8 + j];
            d1s[t * 9 + e] = (float)(acc > 0.0 ? acc : 0.0);
        }
    }
    __syncthreads();

    for (int idx = tid; idx < TOK * NBANDS; idx += 512) {
        int t = idx & 15, c = idx >> 4;
        if (ptok[t] < 0) continue;
        double acc = (double)bd2[c];
        const float* w = Wd2 + c * 8;
        #pragma unroll
        for (int e = 0; e < 8; ++e) acc += (double)d1s[t * 9 + e] * (double)w[e];
        out[REC_OFF + (size_t)c * NPIX + ptok[t]] = (float)acc;
    }
}

// ---------------- launch ----------------
extern "C" void kernel_launch(void* const* d_in, const int* in_sizes, int n_in,
                              void* d_out, int out_size, void* d_ws, size_t ws_size,
                              hipStream_t stream) {
    if (ws_size < WS_NEED) {
        sentinel_kernel<<<dim3(256), dim3(256), 0, stream>>>((float*)d_out, -777.0f);
        return;
    }
    if (out_size != OUT_EXPECT) {
        sentinel_kernel<<<dim3(1), dim3(1), 0, stream>>>((float*)d_out, 1.0e6f);
        return;
    }
    const float* x    = (const float*)d_in[0];
    const float* xo   = (const float*)d_in[1];
    const float* pos  = (const float*)d_in[2];
    const float* bi   = (const float*)d_in[3];
    const float* Wv   = (const float*)d_in[4];
    const float* bv   = (const float*)d_in[5];
    const float* Wo   = (const float*)d_in[6];
    const float* bo   = (const float*)d_in[7];
    const float* ln1w = (const float*)d_in[8];
    const float* ln1b = (const float*)d_in[9];
    const float* W1   = (const float*)d_in[10];
    const float* b1   = (const float*)d_in[11];
    const float* W2   = (const float*)d_in[12];
    const float* b2   = (const float*)d_in[13];
    const float* ln2w = (const float*)d_in[14];
    const float* ln2b = (const float*)d_in[15];
    const float* We1  = (const float*)d_in[16];
    const float* be1  = (const float*)d_in[17];
    const float* We2  = (const float*)d_in[18];
    const float* be2  = (const float*)d_in[19];
    const float* Wd1  = (const float*)d_in[20];
    const float* bd1  = (const float*)d_in[21];
    const float* Wd2  = (const float*)d_in[22];
    const float* bd2  = (const float*)d_in[23];

    char* wsb = (char*)d_ws;
    double* WvoT = (double*)(wsb + WSB_WVOT);
    double* bvo  = (double*)(wsb + WSB_BVO);
    double* sigd = (double*)(wsb + WSB_SIG);
    float*  W1Tf = (float*)(wsb + WSB_W1T);
    float*  W2Tf = (float*)(wsb + WSB_W2T);
    float*  WvoP = (float*)(wsb + WSB_WVP);
    float*  W2P  = (float*)(wsb + WSB_W2P);
    int*    cnt  = (int*)(wsb + WSB_CNT);
    int*    list = (int*)(wsb + WSB_LIST);

    zero_cnt<<<dim3(1), dim3(64), 0, stream>>>(cnt);
    prep_wvot<<<dim3(800), dim3(512), 0, stream>>>(Wv, Wo, WvoT);
    prep_transpose<<<dim3(400), dim3(256), 0, stream>>>(W1, W2, W1Tf, W2Tf);
    prep_padf<<<dim3(800), dim3(512), 0, stream>>>(WvoT, W2Tf, WvoP, W2P);
    prep_small<<<dim3(5), dim3(256), 0, stream>>>(Wo, bv, bo, bi, bvo, sigd);

    const int smem_fast = 74432;
    hipFuncSetAttribute((const void*)hbsm_fast,
                        hipFuncAttributeMaxDynamicSharedMemorySize, smem_fast);
    hipLaunchKernelGGL(hbsm_fast, dim3(2048), dim3(512), smem_fast, stream,
                       x, xo, pos, ln1w, ln1b, b1, b2, ln2w, ln2b,
                       We1, be1, We2, be2, Wd1, bd1, Wd2, bd2,
                       bvo, sigd, WvoP, W1Tf, W2P, cnt, list, (float*)d_out);

    const int smem_rep = 74624;
    hipFuncSetAttribute((const void*)hbsm_repair,
                        hipFuncAttributeMaxDynamicSharedMemorySize, smem_rep);
    hipLaunchKernelGGL(hbsm_repair, dim3(1024), dim3(512), smem_rep, stream,
                       x, xo, pos, ln1w, ln1b, b1, b2, ln2w, ln2b,
                       We1, be1, We2, be2, Wd1, bd1, Wd2, bd2,
                       WvoT, bvo, sigd, W1Tf, W2Tf, cnt, list, (float*)d_out);
    (void)in_sizes; (void)n_in;
}